// Round 6
// baseline (188.853 us; speedup 1.0000x reference)
//
#include <hip/hip_runtime.h>
#include <stdint.h>
#include <stddef.h>

// ============================================================================
// HTensorSquare: out[b] = sum_paths alpha * einsum(uvw,ijk,bui,bvj->bwk)
// Irreps in/out: 64x0e + 32x1o + 16x2e  (DIM 240), B = 20000.
// Fused into 3 GEMMs (one per output irrep), A-operand (CG-transformed
// products) generated in registers, B-operand = preprocessed bf16 weights in
// MFMA-fragment tile order (1 KB contiguous per wave-load).
// Round-6 change: MANUAL software pipelining -- each hot loop prefetches the
// next iteration's B-fragments AND LDS scalars into rotating registers
// (pragma-based unrolling demonstrably did not do this: VGPR stayed 64).
// Load-to-use distance = 1 full iteration for vmcnt and lgkmcnt.
// ============================================================================

// ---------------------------------------------------------------------------
// Compile-time Clebsch-Gordan machinery (exact port of the reference numpy).
// ---------------------------------------------------------------------------
namespace cg {

struct Cx { double re, im; };
constexpr Cx cmul(Cx a, Cx b){ return { a.re*b.re - a.im*b.im, a.re*b.im + a.im*b.re }; }

constexpr double fact(int n){ double r = 1.0; for (int i = 2; i <= n; ++i) r *= (double)i; return r; }

constexpr double csqrt(double x){
  if (x <= 0.0) return 0.0;
  double r = x > 1.0 ? x : 1.0;
  for (int i = 0; i < 50; ++i) r = 0.5*(r + x/r);
  return r;
}

constexpr double neg1pow(int k){ return (k % 2 == 0) ? 1.0 : -1.0; }

constexpr double su2_cg(int j1,int m1,int j2,int m2,int j3,int m3){
  if (m3 != m1 + m2) return 0.0;
  int vmin = -j1 + j2 + m3;
  if (-j1 + m1 > vmin) vmin = -j1 + m1;
  if (0 > vmin) vmin = 0;
  int vmax = j2 + j3 + m1;
  if (j3 - j1 + j2 < vmax) vmax = j3 - j1 + j2;
  if (j3 + m3 < vmax) vmax = j3 + m3;
  if (vmax < vmin) return 0.0;
  double C = csqrt((2.0*j3 + 1.0)*fact(j3+j1-j2)*fact(j3-j1+j2)*fact(j1+j2-j3)
                   *fact(j3+m3)*fact(j3-m3)
                   /(fact(j1+j2+j3+1)*fact(j1-m1)*fact(j1+m1)*fact(j2-m2)*fact(j2+m2)));
  double S = 0.0;
  for (int v = vmin; v <= vmax; ++v)
    S += neg1pow(v + j2 + m2)*fact(j2+j3+m1-v)*fact(j1-m1+v)
       /(fact(v)*fact(j3-j1+j2-v)*fact(j3+m3-v)*fact(v+j1-j2-m3));
  return C*S;
}

struct QM { Cx v[5][5]; };
constexpr QM qmat(int l){
  QM q{};
  const double r2 = 0.70710678118654752440;
  for (int m = -l; m < 0; ++m){
    q.v[l+m][l-m] = Cx{ r2, 0.0 };       // q[l+m, l+|m|]
    q.v[l+m][l+m] = Cx{ 0.0, -r2 };      // q[l+m, l-|m|]
  }
  q.v[l][l] = Cx{ 1.0, 0.0 };
  for (int m = 1; m <= l; ++m){
    double s = neg1pow(m)*r2;
    q.v[l+m][l+m] = Cx{ s, 0.0 };
    q.v[l+m][l-m] = Cx{ 0.0, s };
  }
  Cx ph = (l % 4 == 0) ? Cx{1,0} : (l % 4 == 1) ? Cx{0,-1} : (l % 4 == 2) ? Cx{-1,0} : Cx{0,1};
  QM out{};
  for (int i = 0; i < 5; ++i) for (int j = 0; j < 5; ++j) out.v[i][j] = cmul(ph, q.v[i][j]);
  return out;
}

struct CGT { double v[5][5][5]; };
// Real-basis CG * sqrt(2*l3+1)   (matches reference CGS entries)
constexpr CGT cg_tab(int l1,int l2,int l3){
  double C[5][5][5] = {};
  for (int m1 = -l1; m1 <= l1; ++m1)
    for (int m2 = -l2; m2 <= l2; ++m2)
      for (int m3 = -l3; m3 <= l3; ++m3)
        C[l1+m1][l2+m2][l3+m3] = su2_cg(l1,m1,l2,m2,l3,m3);
  QM Q1 = qmat(l1), Q2 = qmat(l2), Q3 = qmat(l3);
  const int n1 = 2*l1+1, n2 = 2*l2+1, n3 = 2*l3+1;
  const double norm = csqrt(2.0*l3 + 1.0);
  CGT R{};
  for (int j = 0; j < n1; ++j)
    for (int l = 0; l < n2; ++l)
      for (int m = 0; m < n3; ++m){
        Cx s{0,0};
        for (int i = 0; i < n1; ++i)
          for (int k = 0; k < n2; ++k)
            for (int n = 0; n < n3; ++n){
              double c = C[i][k][n];
              if (c != 0.0){
                Cx q3c{ Q3.v[n][m].re, -Q3.v[n][m].im };   // conj(Q3.T)[m][n]
                Cx t = cmul(cmul(Q1.v[i][j], Q2.v[k][l]), q3c);
                s.re += t.re*c; s.im += t.im*c;
              }
            }
        R.v[j][l][m] = s.re * norm;
      }
  return R;
}

constexpr double tab_sumsq(const CGT& t, int n1, int n2, int n3){
  double s = 0;
  for (int i = 0; i < n1; ++i) for (int j = 0; j < n2; ++j) for (int k = 0; k < n3; ++k)
    s += t.v[i][j][k]*t.v[i][j][k];
  return s;
}

} // namespace cg

// Full tables for the 4 non-trivial paths
constexpr cg::CGT T121 = cg::cg_tab(1,2,1);
constexpr cg::CGT T211 = cg::cg_tab(2,1,1);
constexpr cg::CGT T112 = cg::cg_tab(1,1,2);
constexpr cg::CGT T222 = cg::cg_tab(2,2,2);
// Scalar constants for delta-structured paths
constexpr double C000 = cg::cg_tab(0,0,0).v[0][0][0];
constexpr double C011 = cg::cg_tab(0,1,1).v[0][0][0];
constexpr double C022 = cg::cg_tab(0,2,2).v[0][0][0];
constexpr double C101 = cg::cg_tab(1,0,1).v[0][0][0];
constexpr double C110 = cg::cg_tab(1,1,0).v[0][0][0];
constexpr double C220 = cg::cg_tab(2,2,0).v[0][0][0];
constexpr double C202 = cg::cg_tab(2,0,2).v[0][0][0];

// Sanity: Frobenius norm of scaled real CG = (2*l3+1)^2 ; magnitudes of deltas.
static_assert(C000 > 0.99 && C000 < 1.01, "C000");
static_assert(C011 > 1.72 && C011 < 1.74, "C011");                 // sqrt(3)
static_assert(C101 > 1.72 && C101 < 1.74, "C101");
static_assert(C022 > 2.22 && C022 < 2.25, "C022");                 // sqrt(5)
static_assert(C202 > 2.22 && C202 < 2.25, "C202");
static_assert(C110*C110 > 0.332 && C110*C110 < 0.334, "C110");     // 1/3
static_assert(C220*C220 > 0.199 && C220*C220 < 0.201, "C220");     // 1/5
static_assert(cg::tab_sumsq(T121,3,5,3) > 8.9  && cg::tab_sumsq(T121,3,5,3) < 9.1,  "T121");
static_assert(cg::tab_sumsq(T211,5,3,3) > 8.9  && cg::tab_sumsq(T211,5,3,3) < 9.1,  "T211");
static_assert(cg::tab_sumsq(T112,3,3,5) > 24.9 && cg::tab_sumsq(T112,3,3,5) < 25.1, "T112");
static_assert(cg::tab_sumsq(T222,5,5,5) > 24.9 && cg::tab_sumsq(T222,5,5,5) < 25.1, "T222");

// Normalization (fan-in per output irrep) folded into weights
constexpr double A0 = 1.0/cg::csqrt(5376.0);
constexpr double A1 = 1.0/cg::csqrt(5120.0);
constexpr double A2 = 1.0/cg::csqrt(3328.0);

constexpr double S000 = A0*C000, S110 = A0*C110, S220 = A0*C220;
constexpr double S011 = A1*C011, S101 = A1*C101, S121 = A1, S211 = A1;
constexpr double S022 = A2*C022, S112 = A2,      S202 = A2*C202, S222 = A2;

// K extents and workspace offsets (bf16 elements).
// Fragment-tiled layout: element (n = nt*16+col, k = s*32 + kk) lives at
//   base_g + (s*NT_g + nt)*512 + col*32 + kk
// so one wave's (s,nt) B-fragment load is 1024 contiguous bytes.
constexpr int K0 = 5376, K1 = 5120, K2 = 3328;     // S0=168, S1=160, S2=104
constexpr int WT1_OFF = 64*K0;              // 344064  (= 168*4*512)
constexpr int WT2_OFF = WT1_OFF + 32*K1;    // 507904  (= prev + 160*2*512)

// ---------------------------------------------------------------------------
// Device helpers
// ---------------------------------------------------------------------------
using short8  = __attribute__((ext_vector_type(8))) short;
using float4v = __attribute__((ext_vector_type(4))) float;

__device__ __forceinline__ unsigned pkbf(float lo, float hi){
  // truncate both to bf16, pack: [hi.b3 hi.b2 lo.b3 lo.b2] -> one v_perm_b32
  unsigned a = __builtin_bit_cast(unsigned, lo);
  unsigned b = __builtin_bit_cast(unsigned, hi);
  return __builtin_amdgcn_perm(b, a, 0x07060302u);
}

__device__ __forceinline__ short8 mkfrag(const float* s){
  union { short8 v; unsigned u[4]; } f;
  f.u[0] = pkbf(s[0], s[1]);
  f.u[1] = pkbf(s[2], s[3]);
  f.u[2] = pkbf(s[4], s[5]);
  f.u[3] = pkbf(s[6], s[7]);
  return f.v;
}

__device__ __forceinline__ short8 ldB(const unsigned short* p){
  return *reinterpret_cast<const short8*>(p);   // global_load_dwordx4
}

__device__ __forceinline__ float4v MFMA(short8 a, short8 b, float4v c){
  return __builtin_amdgcn_mfma_f32_16x16x32_bf16(a, b, c, 0, 0, 0);
}

__device__ __forceinline__ unsigned short f2bf_rne(float f){
  unsigned u = __builtin_bit_cast(unsigned, f);
  u += 0x7fffu + ((u >> 16) & 1u);
  return (unsigned short)(u >> 16);
}

#define NZ(c) ((c) > 1e-12 || (c) < -1e-12)

constexpr int XS = 244;   // x-tile LDS row stride (floats): 16B aligned, 2-way banks

// ---------------------------------------------------------------------------
// Weight preprocessing v2: fragment-tiled bf16 output, coalesced both sides.
// grid (168, 3), block 256.  blockIdx.x = s (32-wide K slab), blockIdx.y = g.
// ---------------------------------------------------------------------------
__global__ __launch_bounds__(256)
void tsq_prep(const float* __restrict__ w0, const float* __restrict__ w1,
              const float* __restrict__ w2, const float* __restrict__ w3,
              const float* __restrict__ w4, const float* __restrict__ w5,
              const float* __restrict__ w6, const float* __restrict__ w7,
              const float* __restrict__ w8, const float* __restrict__ w9,
              const float* __restrict__ w10, unsigned short* __restrict__ wt){
  const int s   = blockIdx.x;
  const int g   = blockIdx.y;
  const int tid = threadIdx.x;

  const int lw  = 6 - g;                 // log2(Wn): 6,5,4
  const int Wn  = 1 << lw;               // 64,32,16
  const int NT  = Wn >> 4;               // 4,2,1
  int Smax;
  unsigned short* obase;
  if (g == 0){ Smax = 168; obase = wt; }
  else if (g == 1){ Smax = 160; obase = wt + WT1_OFF; }
  else { Smax = 104; obase = wt + WT2_OFF; }
  if (s >= Smax) return;

  __shared__ unsigned short tl[32*66];   // max 32 x (64+2)
  const int st = Wn + 2;                 // LDS row stride (ushorts), bank-safe

  // ---- phase 1: gather/scale/convert, coalesced in n ----
  const int nel = 32 << lw;              // == NT*512
  for (int idx = tid; idx < nel; idx += 256){
    const int kk = idx >> lw, n = idx & (Wn - 1);
    const int k  = s*32 + kk;
    float v;
    if (g == 0){
      if (k < 4096)       v = w0[k*64 + n] * (float)S000;                 // (0,0,0) K=u*64+v
      else if (k < 5120)  v = w4[(k-4096)*64 + n] * (float)S110;          // (1,1,0) K=u*32+v
      else                v = w9[(k-5120)*64 + n] * (float)S220;          // (2,2,0) K=u*16+v
    } else if (g == 1){
      if (k < 2048){                                  // (0,1,1) reordered K=v*64+u
        const int u = k & 63, vv = k >> 6;
        v = w1[(u*32 + vv)*32 + n] * (float)S011;
      } else if (k < 4096){                           // (1,0,1) natural K=u*64+v
        v = w3[(k-2048)*32 + n] * (float)S101;
      } else if (k < 4608){                           // (1,2,1) reordered K=v*32+u
        const int kl = k - 4096; const int u = kl & 31, vv = kl >> 5;
        v = w6[(u*16 + vv)*32 + n] * (float)S121;
      } else {                                        // (2,1,1) natural K=u*32+v
        v = w8[(k-4608)*32 + n] * (float)S211;
      }
    } else {
      if (k < 1024){                                  // (0,2,2) reordered K=v*64+u
        const int u = k & 63, vv = k >> 6;
        v = w2[(u*16 + vv)*16 + n] * (float)S022;
      } else if (k < 2048){                           // (1,1,2) natural K=u*32+v
        v = w5[(k-1024)*16 + n] * (float)S112;
      } else if (k < 3072){                           // (2,0,2) natural K=u*64+v
        v = w7[(k-2048)*16 + n] * (float)S202;
      } else {                                        // (2,2,2) natural K=u*16+v
        v = w10[(k-3072)*16 + n] * (float)S222;
      }
    }
    tl[kk*st + n] = f2bf_rne(v);
  }
  __syncthreads();

  // ---- phase 2: contiguous fragment-order write ----
  unsigned short* o = obase + (size_t)s*NT*512;
  const int nout = NT*512;
  for (int idx = tid; idx < nout; idx += 256){
    const int nt  = idx >> 9;
    const int r   = idx & 511;
    const int col = r >> 5;
    const int kk  = r & 31;
    o[idx] = tl[kk*st + nt*16 + col];
  }
}

// ---------------------------------------------------------------------------
// Main kernel.  grid (3, 313), block 512 (8 waves).  blockIdx.x = GEMM id,
// blockIdx.y = batch tile of 64 rows.  LDS 62.5 KB -> 2 blocks/CU = 16 wv/CU.
// GEMM0: waves = 2 M-halves x 4 K-quarters; GEMM1/2: 4 M-quarters x 2 K-halves.
// Hot loops manually software-pipelined: next iteration's B + LDS scalars
// prefetched into rotating registers before current iteration's compute.
// ---------------------------------------------------------------------------
__global__ __launch_bounds__(512, 4)
void tsq_main(const float* __restrict__ x, const unsigned short* __restrict__ wt,
              float* __restrict__ out){
  __shared__ float lx[64*XS];
  const int g    = blockIdx.x;
  const int b0   = blockIdx.y * 64;
  const int tid  = threadIdx.x;
  const int wv   = tid >> 6;      // 0..7
  const int lane = tid & 63;
  const int col  = lane & 15;
  const int tg   = lane >> 4;
  const int fo   = col*32 + tg*8; // per-lane fragment offset within a 512-el tile

  // ---- stage x tile (fp32, float4) ----
  for (int i = tid; i < 64*60; i += 512){
    const int r = i / 60, c = i - r*60;
    int gb = b0 + r; if (gb > 19999) gb = 19999;
    const float4 v = *(reinterpret_cast<const float4*>(x + (size_t)gb*240) + c);
    *reinterpret_cast<float4*>(&lx[r*XS + c*4]) = v;
  }
  __syncthreads();

  const float4v z4 = {0.f, 0.f, 0.f, 0.f};

  if (g == 0){
    // ====== GEMM 0: out[:,0:64], K=5376, 2-way M (mh) x 4-way K (kh) ======
    const unsigned short* bpl = wt + fo;
    const int mh  = wv >> 2;      // 0..1 : rows [mh*32, mh*32+32)
    const int kh  = wv & 3;       // 0..3 : s = kh, kh+4, ...
    const int par = kh & 1;       // s-parity (constant per wave)

    float4v acc[2][4];
    #pragma unroll
    for (int mt = 0; mt < 2; ++mt)
      #pragma unroll
      for (int nt = 0; nt < 4; ++nt) acc[mt][nt] = z4;

    const float* rbase[2];
    #pragma unroll
    for (int mt = 0; mt < 2; ++mt) rbase[mt] = &lx[(mh*32 + mt*16 + col)*XS];

    // x0 half-window per mt (parity fixed): w8a[mt][t] = x0[par*32 + tg*8 + t]
    float w8a[2][8];
    #pragma unroll
    for (int mt = 0; mt < 2; ++mt){
      const float4 v0 = *reinterpret_cast<const float4*>(rbase[mt] + par*32 + tg*8);
      const float4 v1 = *reinterpret_cast<const float4*>(rbase[mt] + par*32 + tg*8 + 4);
      w8a[mt][0]=v0.x; w8a[mt][1]=v0.y; w8a[mt][2]=v0.z; w8a[mt][3]=v0.w;
      w8a[mt][4]=v1.x; w8a[mt][5]=v1.y; w8a[mt][6]=v1.z; w8a[mt][7]=v1.w;
    }

    // --- (0,0,0): s in [0,128) step 4, K=u*64+v, u = s>>1 --- (pipelined)
    {
      short8 bfc[4]; float xuc[2];
      #pragma unroll
      for (int nt = 0; nt < 4; ++nt) bfc[nt] = ldB(bpl + (kh*4 + nt)*512);
      xuc[0] = rbase[0][kh>>1]; xuc[1] = rbase[1][kh>>1];
      #pragma unroll 2
      for (int s = kh; s < 128; s += 4){
        const int sn = (s + 4 < 128) ? s + 4 : s;
        short8 bfn[4]; float xun[2];
        #pragma unroll
        for (int nt = 0; nt < 4; ++nt) bfn[nt] = ldB(bpl + (sn*4 + nt)*512);
        xun[0] = rbase[0][sn>>1]; xun[1] = rbase[1][sn>>1];
        #pragma unroll
        for (int mt = 0; mt < 2; ++mt){
          float sv[8];
          #pragma unroll
          for (int t = 0; t < 8; ++t) sv[t] = xuc[mt] * w8a[mt][t];
          const short8 af = mkfrag(sv);
          #pragma unroll
          for (int nt = 0; nt < 4; ++nt) acc[mt][nt] = MFMA(af, bfc[nt], acc[mt][nt]);
        }
        #pragma unroll
        for (int nt = 0; nt < 4; ++nt) bfc[nt] = bfn[nt];
        xuc[0] = xun[0]; xuc[1] = xun[1];
      }
    }
    // --- (1,1,0): s in [128,160) step 4, K=u*32+v --- (pipelined)
    float x1w[2][24];
    #pragma unroll
    for (int mt = 0; mt < 2; ++mt)
      #pragma unroll
      for (int q = 0; q < 6; ++q){
        const float4 v = *reinterpret_cast<const float4*>(rbase[mt] + 64 + tg*24 + q*4);
        x1w[mt][q*4+0] = v.x; x1w[mt][q*4+1] = v.y;
        x1w[mt][q*4+2] = v.z; x1w[mt][q*4+3] = v.w;
      }
    {
      short8 bfc[4]; float uc[2][3];
      {
        const int s0 = 128 + kh, u = s0 - 128;
        #pragma unroll
        for (int nt = 0; nt < 4; ++nt) bfc[nt] = ldB(bpl + (s0*4 + nt)*512);
        #pragma unroll
        for (int mt = 0; mt < 2; ++mt){
          uc[mt][0] = rbase[mt][64+u*3]; uc[mt][1] = rbase[mt][64+u*3+1]; uc[mt][2] = rbase[mt][64+u*3+2];
        }
      }
      #pragma unroll 2
      for (int s = 128 + kh; s < 160; s += 4){
        const int sn = (s + 4 < 160) ? s + 4 : s;
        const int un = sn - 128;
        short8 bfn[4]; float unx[2][3];
        #pragma unroll
        for (int nt = 0; nt < 4; ++nt) bfn[nt] = ldB(bpl + (sn*4 + nt)*512);
        #pragma unroll
        for (int mt = 0; mt < 2; ++mt){
          unx[mt][0] = rbase[mt][64+un*3]; unx[mt][1] = rbase[mt][64+un*3+1]; unx[mt][2] = rbase[mt][64+un*3+2];
        }
        #pragma unroll
        for (int mt = 0; mt < 2; ++mt){
          float sv[8];
          #pragma unroll
          for (int t = 0; t < 8; ++t)
            sv[t] = fmaf(uc[mt][0], x1w[mt][t*3], fmaf(uc[mt][1], x1w[mt][t*3+1], uc[mt][2]*x1w[mt][t*3+2]));
          const short8 af = mkfrag(sv);
          #pragma unroll
          for (int nt = 0; nt < 4; ++nt) acc[mt][nt] = MFMA(af, bfc[nt], acc[mt][nt]);
        }
        #pragma unroll
        for (int nt = 0; nt < 4; ++nt) bfc[nt] = bfn[nt];
        #pragma unroll
        for (int mt = 0; mt < 2; ++mt){
          uc[mt][0] = unx[mt][0]; uc[mt][1] = unx[mt][1]; uc[mt][2] = unx[mt][2];
        }
      }
    }
    // --- (2,2,0): s in [160,168) step 4, K=u*16+v --- (2 iters, unpipelined)
    for (int s = 160 + kh; s < 168; s += 4){
      short8 bf[4];
      #pragma unroll
      for (int nt = 0; nt < 4; ++nt) bf[nt] = ldB(bpl + (s*4 + nt)*512);
      const int ub = (s - 160)*2 + (tg >> 1);
      #pragma unroll
      for (int mt = 0; mt < 2; ++mt){
        const float* rb = rbase[mt];
        float xu[5];
        #pragma unroll
        for (int i = 0; i < 5; ++i) xu[i] = rb[160 + ub*5 + i];
        float xv[40];
        #pragma unroll
        for (int q = 0; q < 10; ++q){
          const float4 v = *reinterpret_cast<const float4*>(rb + 160 + (tg&1)*40 + q*4);
          xv[q*4+0] = v.x; xv[q*4+1] = v.y; xv[q*4+2] = v.z; xv[q*4+3] = v.w;
        }
        float sv[8];
        #pragma unroll
        for (int t = 0; t < 8; ++t){
          float a = 0.f;
          #pragma unroll
          for (int i = 0; i < 5; ++i) a = fmaf(xu[i], xv[t*5+i], a);
          sv[t] = a;
        }
        const short8 af = mkfrag(sv);
        #pragma unroll
        for (int nt = 0; nt < 4; ++nt) acc[mt][nt] = MFMA(af, bf[nt], acc[mt][nt]);
      }
    }
    // --- 4-way K reduction + store ---
    __syncthreads();
    float* red = lx;
    if (kh != 0){
      #pragma unroll
      for (int mt = 0; mt < 2; ++mt)
        #pragma unroll
        for (int nt = 0; nt < 4; ++nt)
          #pragma unroll
          for (int r = 0; r < 4; ++r)
            red[mh*6144 + ((kh-1)*8 + mt*4 + nt)*256 + (tg*4 + r)*16 + col] = acc[mt][nt][r];
    }
    __syncthreads();
    if (kh == 0){
      #pragma unroll
      for (int mt = 0; mt < 2; ++mt)
        #pragma unroll
        for (int r = 0; r < 4; ++r){
          const int b = b0 + mh*32 + mt*16 + tg*4 + r;
          if (b < 20000){
            #pragma unroll
            for (int nt = 0; nt < 4; ++nt){
              float v = acc[mt][nt][r];
              #pragma unroll
              for (int w2 = 1; w2 < 4; ++w2)
                v += red[mh*6144 + ((w2-1)*8 + mt*4 + nt)*256 + (tg*4 + r)*16 + col];
              out[(size_t)b*240 + nt*16 + col] = v;
            }
          }
        }
    }

  } else if (g == 1){
    // ===== GEMM 1: out[:,64:160] (w*3+k), K=5120, 4-way M (mq) x 2-way K =====
    const unsigned short* bpl = wt + WT1_OFF + fo;
    const int mq = wv >> 1;       // 0..3 : rows [mq*16, mq*16+16)
    const int kh = wv & 1;
    const float* rb = &lx[(mq*16 + col)*XS];

    float4v acc[3][2];
    #pragma unroll
    for (int k3 = 0; k3 < 3; ++k3)
      #pragma unroll
      for (int nt = 0; nt < 2; ++nt) acc[k3][nt] = z4;

    float w8[8];
    {
      const float4 v0 = *reinterpret_cast<const float4*>(rb + kh*32 + tg*8);
      const float4 v1 = *reinterpret_cast<const float4*>(rb + kh*32 + tg*8 + 4);
      w8[0]=v0.x; w8[1]=v0.y; w8[2]=v0.z; w8[3]=v0.w;
      w8[4]=v1.x; w8[5]=v1.y; w8[6]=v1.z; w8[7]=v1.w;
    }
    float x1w[24];
    #pragma unroll
    for (int q = 0; q < 6; ++q){
      const float4 v = *reinterpret_cast<const float4*>(rb + 64 + tg*24 + q*4);
      x1w[q*4+0] = v.x; x1w[q*4+1] = v.y; x1w[q*4+2] = v.z; x1w[q*4+3] = v.w;
    }

    // --- (0,1,1) [K reordered v*64+u] and (1,0,1) [natural], merged --- (pipelined)
    {
      short8 b0c, b1c; float cc0, cc1, cc2;
      {
        const int m0 = (kh >> 1) & 31;
        b0c = ldB(bpl + (kh*2)*512); b1c = ldB(bpl + (kh*2 + 1)*512);
        cc0 = rb[64+m0*3]; cc1 = rb[64+m0*3+1]; cc2 = rb[64+m0*3+2];
      }
      #pragma unroll 2
      for (int s = kh; s < 128; s += 2){
        const int sn = (s + 2 < 128) ? s + 2 : s;
        const int mn = (sn >> 1) & 31;
        const short8 b0n = ldB(bpl + (sn*2)*512);
        const short8 b1n = ldB(bpl + (sn*2 + 1)*512);
        const float cn0 = rb[64+mn*3], cn1 = rb[64+mn*3+1], cn2 = rb[64+mn*3+2];
        float sv0[8], sv1[8], sv2[8];
        #pragma unroll
        for (int t = 0; t < 8; ++t){
          const float xw = w8[t];
          sv0[t] = xw*cc0; sv1[t] = xw*cc1; sv2[t] = xw*cc2;
        }
        const short8 a0 = mkfrag(sv0), a1 = mkfrag(sv1), a2 = mkfrag(sv2);
        acc[0][0] = MFMA(a0, b0c, acc[0][0]);
        acc[0][1] = MFMA(a0, b1c, acc[0][1]);
        acc[1][0] = MFMA(a1, b0c, acc[1][0]);
        acc[1][1] = MFMA(a1, b1c, acc[1][1]);
        acc[2][0] = MFMA(a2, b0c, acc[2][0]);
        acc[2][1] = MFMA(a2, b1c, acc[2][1]);
        b0c = b0n; b1c = b1n; cc0 = cn0; cc1 = cn1; cc2 = cn2;
      }
    }
    // --- (1,2,1): s in [128,144), reordered K=v*32+u --- (pipelined)
    {
      short8 b0c, b1c; float xqc[5];
      {
        const int s0 = 128 + kh, v2 = s0 - 128;
        b0c = ldB(bpl + (s0*2)*512); b1c = ldB(bpl + (s0*2 + 1)*512);
        #pragma unroll
        for (int j = 0; j < 5; ++j) xqc[j] = rb[160 + v2*5 + j];
      }
      #pragma unroll 2
      for (int s = 128 + kh; s < 144; s += 2){
        const int sn = (s + 2 < 144) ? s + 2 : s;
        const int vn = sn - 128;
        const short8 b0n = ldB(bpl + (sn*2)*512);
        const short8 b1n = ldB(bpl + (sn*2 + 1)*512);
        float xqn[5];
        #pragma unroll
        for (int j = 0; j < 5; ++j) xqn[j] = rb[160 + vn*5 + j];
        float sv0[8], sv1[8], sv2[8];
        #pragma unroll
        for (int t = 0; t < 8; ++t){
          float s3[3] = {0.f, 0.f, 0.f};
          #pragma unroll
          for (int i = 0; i < 3; ++i){
            const float ai = x1w[t*3 + i];
            #pragma unroll
            for (int j = 0; j < 5; ++j){
              const float p = ai * xqc[j];
              #pragma unroll
              for (int kk = 0; kk < 3; ++kk){
                const double cd = T121.v[i][j][kk];
                if (NZ(cd)) s3[kk] = fmaf((float)cd, p, s3[kk]);
              }
            }
          }
          sv0[t] = s3[0]; sv1[t] = s3[1]; sv2[t] = s3[2];
        }
        const short8 a0 = mkfrag(sv0), a1 = mkfrag(sv1), a2 = mkfrag(sv2);
        acc[0][0] = MFMA(a0, b0c, acc[0][0]);
        acc[0][1] = MFMA(a0, b1c, acc[0][1]);
        acc[1][0] = MFMA(a1, b0c, acc[1][0]);
        acc[1][1] = MFMA(a1, b1c, acc[1][1]);
        acc[2][0] = MFMA(a2, b0c, acc[2][0]);
        acc[2][1] = MFMA(a2, b1c, acc[2][1]);
        b0c = b0n; b1c = b1n;
        #pragma unroll
        for (int j = 0; j < 5; ++j) xqc[j] = xqn[j];
      }
    }
    // --- (2,1,1): s in [144,160), natural K=u*32+v --- (pipelined)
    {
      short8 b0c, b1c; float xqc[5];
      {
        const int s0 = 144 + kh, u2 = s0 - 144;
        b0c = ldB(bpl + (s0*2)*512); b1c = ldB(bpl + (s0*2 + 1)*512);
        #pragma unroll
        for (int i = 0; i < 5; ++i) xqc[i] = rb[160 + u2*5 + i];
      }
      #pragma unroll 2
      for (int s = 144 + kh; s < 160; s += 2){
        const int sn = (s + 2 < 160) ? s + 2 : s;
        const int un = sn - 144;
        const short8 b0n = ldB(bpl + (sn*2)*512);
        const short8 b1n = ldB(bpl + (sn*2 + 1)*512);
        float xqn[5];
        #pragma unroll
        for (int i = 0; i < 5; ++i) xqn[i] = rb[160 + un*5 + i];
        float sv0[8], sv1[8], sv2[8];
        #pragma unroll
        for (int t = 0; t < 8; ++t){
          float s3[3] = {0.f, 0.f, 0.f};
          #pragma unroll
          for (int j = 0; j < 3; ++j){
            const float aj = x1w[t*3 + j];
            #pragma unroll
            for (int i = 0; i < 5; ++i){
              const float p = xqc[i] * aj;
              #pragma unroll
              for (int kk = 0; kk < 3; ++kk){
                const double cd = T211.v[i][j][kk];
                if (NZ(cd)) s3[kk] = fmaf((float)cd, p, s3[kk]);
              }
            }
          }
          sv0[t] = s3[0]; sv1[t] = s3[1]; sv2[t] = s3[2];
        }
        const short8 a0 = mkfrag(sv0), a1 = mkfrag(sv1), a2 = mkfrag(sv2);
        acc[0][0] = MFMA(a0, b0c, acc[0][0]);
        acc[0][1] = MFMA(a0, b1c, acc[0][1]);
        acc[1][0] = MFMA(a1, b0c, acc[1][0]);
        acc[1][1] = MFMA(a1, b1c, acc[1][1]);
        acc[2][0] = MFMA(a2, b0c, acc[2][0]);
        acc[2][1] = MFMA(a2, b1c, acc[2][1]);
        b0c = b0n; b1c = b1n;
        #pragma unroll
        for (int i = 0; i < 5; ++i) xqc[i] = xqn[i];
      }
    }
    // --- 2-way K reduction + store (3 consecutive floats per (b,w)) ---
    __syncthreads();
    float* red = lx;
    if (kh == 1){
      #pragma unroll
      for (int k3 = 0; k3 < 3; ++k3)
        #pragma unroll
        for (int nt = 0; nt < 2; ++nt)
          #pragma unroll
          for (int r = 0; r < 4; ++r)
            red[mq*1536 + (k3*2 + nt)*256 + (tg*4 + r)*16 + col] = acc[k3][nt][r];
    }
    __syncthreads();
    if (kh == 0){
      #pragma unroll
      for (int r = 0; r < 4; ++r){
        const int b = b0 + mq*16 + tg*4 + r;
        if (b < 20000){
          #pragma unroll
          for (int nt = 0; nt < 2; ++nt){
            const int w2 = nt*16 + col;
            float* o = out + (size_t)b*240 + 64 + 3*w2;
            #pragma unroll
            for (int k3 = 0; k3 < 3; ++k3)
              o[k3] = acc[k3][nt][r]
                    + red[mq*1536 + (k3*2 + nt)*256 + (tg*4 + r)*16 + col];
          }
        }
      }
    }

  } else {
    // ===== GEMM 2: out[:,160:240] (w*5+k), K=3328, 4-way M (mq) x 2-way K =====
    const unsigned short* bpl = wt + WT2_OFF + fo;
    const int mq = wv >> 1;       // 0..3
    const int kh = wv & 1;
    const float* rb = &lx[(mq*16 + col)*XS];

    float4v acc[5] = { z4, z4, z4, z4, z4 };

    float w8[8];
    {
      const float4 v0 = *reinterpret_cast<const float4*>(rb + kh*32 + tg*8);
      const float4 v1 = *reinterpret_cast<const float4*>(rb + kh*32 + tg*8 + 4);
      w8[0]=v0.x; w8[1]=v0.y; w8[2]=v0.z; w8[3]=v0.w;
      w8[4]=v1.x; w8[5]=v1.y; w8[6]=v1.z; w8[7]=v1.w;
    }
    float x1w[24];
    #pragma unroll
    for (int q = 0; q < 6; ++q){
      const float4 v = *reinterpret_cast<const float4*>(rb + 64 + tg*24 + q*4);
      x1w[q*4+0] = v.x; x1w[q*4+1] = v.y; x1w[q*4+2] = v.z; x1w[q*4+3] = v.w;
    }

    // --- (0,2,2): s in [0,32), reordered K=v*64+u, u-window = w8 --- (pipelined)
    {
      short8 bfc; float xqc[5];
      {
        const int v2 = kh >> 1;
        bfc = ldB(bpl + kh*512);
        #pragma unroll
        for (int j = 0; j < 5; ++j) xqc[j] = rb[160 + v2*5 + j];
      }
      #pragma unroll 2
      for (int s = kh; s < 32; s += 2){
        const int sn = (s + 2 < 32) ? s + 2 : s;
        const int vn = sn >> 1;
        const short8 bfn = ldB(bpl + sn*512);
        float xqn[5];
        #pragma unroll
        for (int j = 0; j < 5; ++j) xqn[j] = rb[160 + vn*5 + j];
        float sv[5][8];
        #pragma unroll
        for (int t = 0; t < 8; ++t){
          const float xw = w8[t];
          #pragma unroll
          for (int k5 = 0; k5 < 5; ++k5) sv[k5][t] = xw * xqc[k5];
        }
        #pragma unroll
        for (int k5 = 0; k5 < 5; ++k5) acc[k5] = MFMA(mkfrag(sv[k5]), bfc, acc[k5]);
        bfc = bfn;
        #pragma unroll
        for (int j = 0; j < 5; ++j) xqc[j] = xqn[j];
      }
    }
    // --- (1,1,2): s in [32,64), natural K=u*32+v --- (pipelined)
    {
      short8 bfc; float xuc[3];
      {
        const int s0 = 32 + kh, u = s0 - 32;
        bfc = ldB(bpl + s0*512);
        #pragma unroll
        for (int i = 0; i < 3; ++i) xuc[i] = rb[64 + u*3 + i];
      }
      #pragma unroll 2
      for (int s = 32 + kh; s < 64; s += 2){
        const int sn = (s + 2 < 64) ? s + 2 : s;
        const int un = sn - 32;
        const short8 bfn = ldB(bpl + sn*512);
        float xun[3];
        #pragma unroll
        for (int i = 0; i < 3; ++i) xun[i] = rb[64 + un*3 + i];
        float sv[5][8];
        #pragma unroll
        for (int t = 0; t < 8; ++t){
          float s5[5] = {0.f,0.f,0.f,0.f,0.f};
          #pragma unroll
          for (int i = 0; i < 3; ++i)
            #pragma unroll
            for (int j = 0; j < 3; ++j){
              const float p = xuc[i] * x1w[t*3 + j];
              #pragma unroll
              for (int kk = 0; kk < 5; ++kk){
                const double cd = T112.v[i][j][kk];
                if (NZ(cd)) s5[kk] = fmaf((float)cd, p, s5[kk]);
              }
            }
          #pragma unroll
          for (int kk = 0; kk < 5; ++kk) sv[kk][t] = s5[kk];
        }
        #pragma unroll
        for (int k5 = 0; k5 < 5; ++k5) acc[k5] = MFMA(mkfrag(sv[k5]), bfc, acc[k5]);
        bfc = bfn;
        xuc[0] = xun[0]; xuc[1] = xun[1]; xuc[2] = xun[2];
      }
    }
    // --- (2,0,2): s in [64,96), natural K=u*64+v, v-window = w8 --- (pipelined)
    {
      short8 bfc; float xqc[5];
      {
        const int s0 = 64 + kh, u2 = (s0 - 64) >> 1;
        bfc = ldB(bpl + s0*512);
        #pragma unroll
        for (int i = 0; i < 5; ++i) xqc[i] = rb[160 + u2*5 + i];
      }
      #pragma unroll 2
      for (int s = 64 + kh; s < 96; s += 2){
        const int sn = (s + 2 < 96) ? s + 2 : s;
        const int un = (sn - 64) >> 1;
        const short8 bfn = ldB(bpl + sn*512);
        float xqn[5];
        #pragma unroll
        for (int i = 0; i < 5; ++i) xqn[i] = rb[160 + un*5 + i];
        float sv[5][8];
        #pragma unroll
        for (int t = 0; t < 8; ++t){
          const float xw = w8[t];
          #pragma unroll
          for (int k5 = 0; k5 < 5; ++k5) sv[k5][t] = xqc[k5] * xw;
        }
        #pragma unroll
        for (int k5 = 0; k5 < 5; ++k5) acc[k5] = MFMA(mkfrag(sv[k5]), bfc, acc[k5]);
        bfc = bfn;
        #pragma unroll
        for (int i = 0; i < 5; ++i) xqc[i] = xqn[i];
      }
    }
    // --- (2,2,2): s in [96,104), natural K=u*16+v --- (4 iters, unpipelined)
    float x2w[40];
    #pragma unroll
    for (int q = 0; q < 10; ++q){
      const float4 v = *reinterpret_cast<const float4*>(rb + 160 + (tg&1)*40 + q*4);
      x2w[q*4+0] = v.x; x2w[q*4+1] = v.y; x2w[q*4+2] = v.z; x2w[q*4+3] = v.w;
    }
    #pragma unroll 1
    for (int s = 96 + kh; s < 104; s += 2){
      const short8 bf = ldB(bpl + s*512);
      const int ub = (s - 96)*2 + (tg >> 1);
      float xu[5];
      #pragma unroll
      for (int i = 0; i < 5; ++i) xu[i] = rb[160 + ub*5 + i];
      float sv[5][8];
      #pragma unroll
      for (int t = 0; t < 8; ++t){
        float s5[5] = {0.f,0.f,0.f,0.f,0.f};
        #pragma unroll
        for (int i = 0; i < 5; ++i)
          #pragma unroll
          for (int j = 0; j < 5; ++j){
            const float p = xu[i] * x2w[t*5 + j];
            #pragma unroll
            for (int kk = 0; kk < 5; ++kk){
              const double cd = T222.v[i][j][kk];
              if (NZ(cd)) s5[kk] = fmaf((float)cd, p, s5[kk]);
            }
          }
        #pragma unroll
        for (int kk = 0; kk < 5; ++kk) sv[kk][t] = s5[kk];
      }
      #pragma unroll
      for (int k5 = 0; k5 < 5; ++k5) acc[k5] = MFMA(mkfrag(sv[k5]), bf, acc[k5]);
    }
    // --- 2-way K reduction + store (5 consecutive floats per (b,w)) ---
    __syncthreads();
    float* red = lx;
    if (kh == 1){
      #pragma unroll
      for (int k5 = 0; k5 < 5; ++k5)
        #pragma unroll
        for (int r = 0; r < 4; ++r)
          red[mq*1280 + k5*256 + (tg*4 + r)*16 + col] = acc[k5][r];
    }
    __syncthreads();
    if (kh == 0){
      #pragma unroll
      for (int r = 0; r < 4; ++r){
        const int b = b0 + mq*16 + tg*4 + r;
        if (b < 20000){
          float* o = out + (size_t)b*240 + 160 + 5*col;
          #pragma unroll
          for (int k5 = 0; k5 < 5; ++k5)
            o[k5] = acc[k5][r] + red[mq*1280 + k5*256 + (tg*4 + r)*16 + col];
        }
      }
    }
  }
}

// ---------------------------------------------------------------------------
extern "C" void kernel_launch(void* const* d_in, const int* in_sizes, int n_in,
                              void* d_out, int out_size, void* d_ws, size_t ws_size,
                              hipStream_t stream){
  (void)in_sizes; (void)n_in; (void)out_size; (void)ws_size;
  const float* x = (const float*)d_in[0];
  const float* w[11];
  for (int i = 0; i < 11; ++i) w[i] = (const float*)d_in[1 + i];
  unsigned short* wt = (unsigned short*)d_ws;
  float* out = (float*)d_out;

  dim3 gp(168, 3);
  tsq_prep<<<gp, 256, 0, stream>>>(w[0], w[1], w[2], w[3], w[4], w[5],
                                   w[6], w[7], w[8], w[9], w[10], wt);
  dim3 gm(3, 313);
  tsq_main<<<gm, 512, 0, stream>>>(x, wt, out);
}

// Round 7
// 167.760 us; speedup vs baseline: 1.1257x; 1.1257x over previous
//
#include <hip/hip_runtime.h>
#include <stdint.h>
#include <stddef.h>

// ============================================================================
// HTensorSquare: out[b] = sum_paths alpha * einsum(uvw,ijk,bui,bvj->bwk)
// Irreps in/out: 64x0e + 32x1o + 16x2e  (DIM 240), B = 20000.
// Fused into 3 GEMMs, A-operand generated in registers, B = preprocessed bf16
// weights in MFMA-fragment tile order.
// Round-7: ALGEBRAIC WORK REDUCTION.
//  (a) mirror-path folding (x@x symmetric => identical A-fragments):
//      (1,0,1)->(0,1,1), (2,0,2)->(0,2,2), (2,1,1)->(1,2,1) [C211=C121^T,
//      static_assert'd].  K1 5120->2560, K2 3328->2304; two loops deleted.
//  (b) (0,0,0) self-symmetry: drop u>=32,v<32 slices, fold into mirrors.
//      K0 5376->4352.
//  (c) CG precontraction in (1,2,1)/(1,1,2)/(2,2,2): hoist
//      t[kk][j] = sum_i C[i][j][kk]*x[i] per K-slice (shared by 8 fragments).
// Manual pipelining removed (rounds 5-6: provably neutral, compiler un-rotates).
// ============================================================================

// ---------------------------------------------------------------------------
// Compile-time Clebsch-Gordan machinery (exact port of the reference numpy).
// ---------------------------------------------------------------------------
namespace cg {

struct Cx { double re, im; };
constexpr Cx cmul(Cx a, Cx b){ return { a.re*b.re - a.im*b.im, a.re*b.im + a.im*b.re }; }

constexpr double fact(int n){ double r = 1.0; for (int i = 2; i <= n; ++i) r *= (double)i; return r; }

constexpr double csqrt(double x){
  if (x <= 0.0) return 0.0;
  double r = x > 1.0 ? x : 1.0;
  for (int i = 0; i < 50; ++i) r = 0.5*(r + x/r);
  return r;
}

constexpr double neg1pow(int k){ return (k % 2 == 0) ? 1.0 : -1.0; }

constexpr double su2_cg(int j1,int m1,int j2,int m2,int j3,int m3){
  if (m3 != m1 + m2) return 0.0;
  int vmin = -j1 + j2 + m3;
  if (-j1 + m1 > vmin) vmin = -j1 + m1;
  if (0 > vmin) vmin = 0;
  int vmax = j2 + j3 + m1;
  if (j3 - j1 + j2 < vmax) vmax = j3 - j1 + j2;
  if (j3 + m3 < vmax) vmax = j3 + m3;
  if (vmax < vmin) return 0.0;
  double C = csqrt((2.0*j3 + 1.0)*fact(j3+j1-j2)*fact(j3-j1+j2)*fact(j1+j2-j3)
                   *fact(j3+m3)*fact(j3-m3)
                   /(fact(j1+j2+j3+1)*fact(j1-m1)*fact(j1+m1)*fact(j2-m2)*fact(j2+m2)));
  double S = 0.0;
  for (int v = vmin; v <= vmax; ++v)
    S += neg1pow(v + j2 + m2)*fact(j2+j3+m1-v)*fact(j1-m1+v)
       /(fact(v)*fact(j3-j1+j2-v)*fact(j3+m3-v)*fact(v+j1-j2-m3));
  return C*S;
}

struct QM { Cx v[5][5]; };
constexpr QM qmat(int l){
  QM q{};
  const double r2 = 0.70710678118654752440;
  for (int m = -l; m < 0; ++m){
    q.v[l+m][l-m] = Cx{ r2, 0.0 };       // q[l+m, l+|m|]
    q.v[l+m][l+m] = Cx{ 0.0, -r2 };      // q[l+m, l-|m|]
  }
  q.v[l][l] = Cx{ 1.0, 0.0 };
  for (int m = 1; m <= l; ++m){
    double s = neg1pow(m)*r2;
    q.v[l+m][l+m] = Cx{ s, 0.0 };
    q.v[l+m][l-m] = Cx{ 0.0, s };
  }
  Cx ph = (l % 4 == 0) ? Cx{1,0} : (l % 4 == 1) ? Cx{0,-1} : (l % 4 == 2) ? Cx{-1,0} : Cx{0,1};
  QM out{};
  for (int i = 0; i < 5; ++i) for (int j = 0; j < 5; ++j) out.v[i][j] = cmul(ph, q.v[i][j]);
  return out;
}

struct CGT { double v[5][5][5]; };
// Real-basis CG * sqrt(2*l3+1)   (matches reference CGS entries)
constexpr CGT cg_tab(int l1,int l2,int l3){
  double C[5][5][5] = {};
  for (int m1 = -l1; m1 <= l1; ++m1)
    for (int m2 = -l2; m2 <= l2; ++m2)
      for (int m3 = -l3; m3 <= l3; ++m3)
        C[l1+m1][l2+m2][l3+m3] = su2_cg(l1,m1,l2,m2,l3,m3);
  QM Q1 = qmat(l1), Q2 = qmat(l2), Q3 = qmat(l3);
  const int n1 = 2*l1+1, n2 = 2*l2+1, n3 = 2*l3+1;
  const double norm = csqrt(2.0*l3 + 1.0);
  CGT R{};
  for (int j = 0; j < n1; ++j)
    for (int l = 0; l < n2; ++l)
      for (int m = 0; m < n3; ++m){
        Cx s{0,0};
        for (int i = 0; i < n1; ++i)
          for (int k = 0; k < n2; ++k)
            for (int n = 0; n < n3; ++n){
              double c = C[i][k][n];
              if (c != 0.0){
                Cx q3c{ Q3.v[n][m].re, -Q3.v[n][m].im };   // conj(Q3.T)[m][n]
                Cx t = cmul(cmul(Q1.v[i][j], Q2.v[k][l]), q3c);
                s.re += t.re*c; s.im += t.im*c;
              }
            }
        R.v[j][l][m] = s.re * norm;
      }
  return R;
}

constexpr double tab_sumsq(const CGT& t, int n1, int n2, int n3){
  double s = 0;
  for (int i = 0; i < n1; ++i) for (int j = 0; j < n2; ++j) for (int k = 0; k < n3; ++k)
    s += t.v[i][j][k]*t.v[i][j][k];
  return s;
}

} // namespace cg

// Full tables for the 4 non-trivial paths
constexpr cg::CGT T121 = cg::cg_tab(1,2,1);
constexpr cg::CGT T211 = cg::cg_tab(2,1,1);
constexpr cg::CGT T112 = cg::cg_tab(1,1,2);
constexpr cg::CGT T222 = cg::cg_tab(2,2,2);
// Scalar constants for delta-structured paths
constexpr double C000 = cg::cg_tab(0,0,0).v[0][0][0];
constexpr double C011 = cg::cg_tab(0,1,1).v[0][0][0];
constexpr double C022 = cg::cg_tab(0,2,2).v[0][0][0];
constexpr double C101 = cg::cg_tab(1,0,1).v[0][0][0];
constexpr double C110 = cg::cg_tab(1,1,0).v[0][0][0];
constexpr double C220 = cg::cg_tab(2,2,0).v[0][0][0];
constexpr double C202 = cg::cg_tab(2,0,2).v[0][0][0];

// Sanity checks
static_assert(C000 > 0.99 && C000 < 1.01, "C000");
static_assert(C011 > 1.72 && C011 < 1.74, "C011");
static_assert(C101 > 1.72 && C101 < 1.74, "C101");
static_assert(C022 > 2.22 && C022 < 2.25, "C022");
static_assert(C202 > 2.22 && C202 < 2.25, "C202");
static_assert(C110*C110 > 0.332 && C110*C110 < 0.334, "C110");
static_assert(C220*C220 > 0.199 && C220*C220 < 0.201, "C220");
static_assert(cg::tab_sumsq(T121,3,5,3) > 8.9  && cg::tab_sumsq(T121,3,5,3) < 9.1,  "T121");
static_assert(cg::tab_sumsq(T211,5,3,3) > 8.9  && cg::tab_sumsq(T211,5,3,3) < 9.1,  "T211");
static_assert(cg::tab_sumsq(T112,3,3,5) > 24.9 && cg::tab_sumsq(T112,3,3,5) < 25.1, "T112");
static_assert(cg::tab_sumsq(T222,5,5,5) > 24.9 && cg::tab_sumsq(T222,5,5,5) < 25.1, "T222");

// The (2,1,1)->(1,2,1) fold requires C211[i][j][k] == C121[j][i][k].
constexpr double t121_t211_swapdiff(){
  double m = 0;
  for (int i = 0; i < 5; ++i)
    for (int j = 0; j < 3; ++j)
      for (int k = 0; k < 3; ++k){
        double d = T211.v[i][j][k] - T121.v[j][i][k];
        if (d < 0) d = -d;
        if (d > m) m = d;
      }
  return m;
}
static_assert(t121_t211_swapdiff() < 1e-9, "T211 != T121^T -- fold invalid");

// Normalization (fan-in per output irrep) folded into weights.
// NOTE: fan-in is a property of the REFERENCE path structure (unchanged).
constexpr double A0 = 1.0/cg::csqrt(5376.0);
constexpr double A1 = 1.0/cg::csqrt(5120.0);
constexpr double A2 = 1.0/cg::csqrt(3328.0);

constexpr double S000 = A0*C000, S110 = A0*C110, S220 = A0*C220;
constexpr double S011 = A1*C011, S101 = A1*C101, S121 = A1, S211 = A1;
constexpr double S022 = A2*C022, S112 = A2,      S202 = A2*C202, S222 = A2;

// Folded K extents (bf16 elements), fragment-tiled layout:
// element (n = nt*16+col, k = s*32+kk) at base_g + (s*NT_g + nt)*512 + col*32 + kk.
// GEMM0: s in [0,64) (0,0,0) u<32 all v (odd slices carry mirror fold);
//        [64,96) (0,0,0) u>=32,v>=32; [96,128) (1,1,0); [128,136) (2,2,0).
// GEMM1: s in [0,64) (0,1,1)+(1,0,1) fold; [64,80) (1,2,1)+(2,1,1) fold.
// GEMM2: s in [0,32) (0,2,2)+(2,0,2) fold; [32,64) (1,1,2); [64,72) (2,2,2).
constexpr int K0 = 4352, K1 = 2560, K2 = 2304;   // S0=136, S1=80, S2=72
constexpr int WT1_OFF = 64*K0;              // 278528
constexpr int WT2_OFF = WT1_OFF + 32*K1;    // 360448

// ---------------------------------------------------------------------------
// Device helpers
// ---------------------------------------------------------------------------
using short8  = __attribute__((ext_vector_type(8))) short;
using float4v = __attribute__((ext_vector_type(4))) float;

__device__ __forceinline__ unsigned pkbf(float lo, float hi){
  unsigned a = __builtin_bit_cast(unsigned, lo);
  unsigned b = __builtin_bit_cast(unsigned, hi);
  return __builtin_amdgcn_perm(b, a, 0x07060302u);
}

__device__ __forceinline__ short8 mkfrag(const float* s){
  union { short8 v; unsigned u[4]; } f;
  f.u[0] = pkbf(s[0], s[1]);
  f.u[1] = pkbf(s[2], s[3]);
  f.u[2] = pkbf(s[4], s[5]);
  f.u[3] = pkbf(s[6], s[7]);
  return f.v;
}

__device__ __forceinline__ short8 ldB(const unsigned short* p){
  return *reinterpret_cast<const short8*>(p);   // global_load_dwordx4
}

__device__ __forceinline__ float4v MFMA(short8 a, short8 b, float4v c){
  return __builtin_amdgcn_mfma_f32_16x16x32_bf16(a, b, c, 0, 0, 0);
}

__device__ __forceinline__ unsigned short f2bf_rne(float f){
  unsigned u = __builtin_bit_cast(unsigned, f);
  u += 0x7fffu + ((u >> 16) & 1u);
  return (unsigned short)(u >> 16);
}

#define NZ(c) ((c) > 1e-12 || (c) < -1e-12)

constexpr int XS = 244;   // x-tile LDS row stride (floats)

// ---------------------------------------------------------------------------
// Weight preprocessing v3: folded + fragment-tiled.
// grid (136, 3), block 256.  blockIdx.x = s (32-wide K slab), blockIdx.y = g.
// ---------------------------------------------------------------------------
__global__ __launch_bounds__(256)
void tsq_prep(const float* __restrict__ w0, const float* __restrict__ w1,
              const float* __restrict__ w2, const float* __restrict__ w3,
              const float* __restrict__ w4, const float* __restrict__ w5,
              const float* __restrict__ w6, const float* __restrict__ w7,
              const float* __restrict__ w8, const float* __restrict__ w9,
              const float* __restrict__ w10, unsigned short* __restrict__ wt){
  const int s   = blockIdx.x;
  const int g   = blockIdx.y;
  const int tid = threadIdx.x;

  const int lw  = 6 - g;                 // log2(Wn): 6,5,4
  const int Wn  = 1 << lw;               // 64,32,16
  const int NT  = Wn >> 4;               // 4,2,1
  int Smax;
  unsigned short* obase;
  if (g == 0){ Smax = 136; obase = wt; }
  else if (g == 1){ Smax = 80; obase = wt + WT1_OFF; }
  else { Smax = 72; obase = wt + WT2_OFF; }
  if (s >= Smax) return;

  __shared__ unsigned short tl[32*66];   // max 32 x (64+2)
  const int st = Wn + 2;

  // ---- phase 1: gather/scale/convert (with mirror folds), coalesced in n ----
  const int nel = 32 << lw;              // == NT*512
  for (int idx = tid; idx < nel; idx += 256){
    const int kk = idx >> lw, n = idx & (Wn - 1);
    float v;
    if (g == 0){
      if (s < 64){                                   // (0,0,0) u<32, all v
        const int u = s >> 1, vv = (s & 1)*32 + kk;
        v = w0[(u*64 + vv)*64 + n];
        if (s & 1) v += w0[(vv*64 + u)*64 + n];      // fold dropped (u>=32,v<32)
        v *= (float)S000;
      } else if (s < 96){                            // (0,0,0) u>=32, v>=32
        const int u = s - 32, vv = 32 + kk;
        v = w0[(u*64 + vv)*64 + n] * (float)S000;
      } else if (s < 128){                           // (1,1,0) K=u*32+v
        v = w4[((s-96)*32 + kk)*64 + n] * (float)S110;
      } else {                                       // (2,2,0) K=u*16+v
        v = w9[((s-128)*32 + kk)*64 + n] * (float)S220;
      }
    } else if (g == 1){
      const int k = s*32 + kk;
      if (s < 64){                                   // (0,1,1)+(1,0,1), K=A1*64+A0
        v = w1[((k&63)*32 + (k>>6))*32 + n] * (float)S011
          + w3[k*32 + n] * (float)S101;
      } else {                                       // (1,2,1)+(2,1,1), K=v2*32+u1
        const int kr = k - 2048;
        const int u1 = kr & 31, v2 = kr >> 5;
        v = w6[(u1*16 + v2)*32 + n] * (float)S121
          + w8[(v2*32 + u1)*32 + n] * (float)S211;
      }
    } else {
      const int k = s*32 + kk;
      if (s < 32){                                   // (0,2,2)+(2,0,2), K=v2*64+u0
        v = w2[((k&63)*16 + (k>>6))*16 + n] * (float)S022
          + w7[k*16 + n] * (float)S202;
      } else if (s < 64){                            // (1,1,2) K=u*32+v
        v = w5[(k-1024)*16 + n] * (float)S112;
      } else {                                       // (2,2,2) K=u*16+v
        v = w10[(k-2048)*16 + n] * (float)S222;
      }
    }
    tl[kk*st + n] = f2bf_rne(v);
  }
  __syncthreads();

  // ---- phase 2: contiguous fragment-order write ----
  unsigned short* o = obase + (size_t)s*NT*512;
  const int nout = NT*512;
  for (int idx = tid; idx < nout; idx += 256){
    const int nt  = idx >> 9;
    const int r   = idx & 511;
    const int col = r >> 5;
    const int kk  = r & 31;
    o[idx] = tl[kk*st + nt*16 + col];
  }
}

// ---------------------------------------------------------------------------
// Main kernel.  grid (3, 313), block 512 (8 waves).  blockIdx.x = GEMM id,
// blockIdx.y = batch tile of 64 rows.  LDS 62.5 KB -> 2 blocks/CU = 16 wv/CU.
// GEMM0: 2-way M (mh) x 4-way K (kh); GEMM1/2: 4-way M (mq) x 2-way K (kh).
// ---------------------------------------------------------------------------
__global__ __launch_bounds__(512, 4)
void tsq_main(const float* __restrict__ x, const unsigned short* __restrict__ wt,
              float* __restrict__ out){
  __shared__ float lx[64*XS];
  const int g    = blockIdx.x;
  const int b0   = blockIdx.y * 64;
  const int tid  = threadIdx.x;
  const int wv   = tid >> 6;      // 0..7
  const int lane = tid & 63;
  const int col  = lane & 15;
  const int tg   = lane >> 4;
  const int fo   = col*32 + tg*8; // per-lane fragment offset within a 512-el tile

  // ---- stage x tile (fp32, float4) ----
  for (int i = tid; i < 64*60; i += 512){
    const int r = i / 60, c = i - r*60;
    int gb = b0 + r; if (gb > 19999) gb = 19999;
    const float4 v = *(reinterpret_cast<const float4*>(x + (size_t)gb*240) + c);
    *reinterpret_cast<float4*>(&lx[r*XS + c*4]) = v;
  }
  __syncthreads();

  const float4v z4 = {0.f, 0.f, 0.f, 0.f};

  if (g == 0){
    // ====== GEMM 0: out[:,0:64], K=4352, 2-way M (mh) x 4-way K (kh) ======
    const unsigned short* bpl = wt + fo;
    const int mh  = wv >> 2;
    const int kh  = wv & 3;
    const int par = kh & 1;       // s-parity for s<64 (constant per wave)

    float4v acc[2][4];
    #pragma unroll
    for (int mt = 0; mt < 2; ++mt)
      #pragma unroll
      for (int nt = 0; nt < 4; ++nt) acc[mt][nt] = z4;

    const float* rbase[2];
    #pragma unroll
    for (int mt = 0; mt < 2; ++mt) rbase[mt] = &lx[(mh*32 + mt*16 + col)*XS];

    // wA = x0 window for parity `par` (used s<64); wB = x0 upper half (s>=64).
    float wA[2][8], wB[2][8];
    #pragma unroll
    for (int mt = 0; mt < 2; ++mt){
      const float4 a0 = *reinterpret_cast<const float4*>(rbase[mt] + par*32 + tg*8);
      const float4 a1 = *reinterpret_cast<const float4*>(rbase[mt] + par*32 + tg*8 + 4);
      wA[mt][0]=a0.x; wA[mt][1]=a0.y; wA[mt][2]=a0.z; wA[mt][3]=a0.w;
      wA[mt][4]=a1.x; wA[mt][5]=a1.y; wA[mt][6]=a1.z; wA[mt][7]=a1.w;
      const float4 b0v = *reinterpret_cast<const float4*>(rbase[mt] + 32 + tg*8);
      const float4 b1v = *reinterpret_cast<const float4*>(rbase[mt] + 32 + tg*8 + 4);
      wB[mt][0]=b0v.x; wB[mt][1]=b0v.y; wB[mt][2]=b0v.z; wB[mt][3]=b0v.w;
      wB[mt][4]=b1v.x; wB[mt][5]=b1v.y; wB[mt][6]=b1v.z; wB[mt][7]=b1v.w;
    }

    // --- (0,0,0) part A: s in [0,64), u = s>>1 (<32), window = wA ---
    for (int s = kh; s < 64; s += 4){
      short8 bf[4];
      #pragma unroll
      for (int nt = 0; nt < 4; ++nt) bf[nt] = ldB(bpl + (s*4 + nt)*512);
      const int u = s >> 1;
      #pragma unroll
      for (int mt = 0; mt < 2; ++mt){
        const float xu = rbase[mt][u];
        float sv[8];
        #pragma unroll
        for (int t = 0; t < 8; ++t) sv[t] = xu * wA[mt][t];
        const short8 af = mkfrag(sv);
        #pragma unroll
        for (int nt = 0; nt < 4; ++nt) acc[mt][nt] = MFMA(af, bf[nt], acc[mt][nt]);
      }
    }
    // --- (0,0,0) part B: s in [64,96), u = s-32 (>=32), window = wB ---
    for (int s = 64 + kh; s < 96; s += 4){
      short8 bf[4];
      #pragma unroll
      for (int nt = 0; nt < 4; ++nt) bf[nt] = ldB(bpl + (s*4 + nt)*512);
      const int u = s - 32;
      #pragma unroll
      for (int mt = 0; mt < 2; ++mt){
        const float xu = rbase[mt][u];
        float sv[8];
        #pragma unroll
        for (int t = 0; t < 8; ++t) sv[t] = xu * wB[mt][t];
        const short8 af = mkfrag(sv);
        #pragma unroll
        for (int nt = 0; nt < 4; ++nt) acc[mt][nt] = MFMA(af, bf[nt], acc[mt][nt]);
      }
    }
    // --- (1,1,0): s in [96,128), u = s-96, K=u*32+v ---
    float x1w[2][24];
    #pragma unroll
    for (int mt = 0; mt < 2; ++mt)
      #pragma unroll
      for (int q = 0; q < 6; ++q){
        const float4 v = *reinterpret_cast<const float4*>(rbase[mt] + 64 + tg*24 + q*4);
        x1w[mt][q*4+0] = v.x; x1w[mt][q*4+1] = v.y;
        x1w[mt][q*4+2] = v.z; x1w[mt][q*4+3] = v.w;
      }
    for (int s = 96 + kh; s < 128; s += 4){
      short8 bf[4];
      #pragma unroll
      for (int nt = 0; nt < 4; ++nt) bf[nt] = ldB(bpl + (s*4 + nt)*512);
      const int u = s - 96;
      #pragma unroll
      for (int mt = 0; mt < 2; ++mt){
        const float* rb = rbase[mt];
        const float u0 = rb[64+u*3], u1 = rb[64+u*3+1], u2 = rb[64+u*3+2];
        float sv[8];
        #pragma unroll
        for (int t = 0; t < 8; ++t)
          sv[t] = fmaf(u0, x1w[mt][t*3], fmaf(u1, x1w[mt][t*3+1], u2*x1w[mt][t*3+2]));
        const short8 af = mkfrag(sv);
        #pragma unroll
        for (int nt = 0; nt < 4; ++nt) acc[mt][nt] = MFMA(af, bf[nt], acc[mt][nt]);
      }
    }
    // --- (2,2,0): s in [128,136), K=u*16+v ---
    for (int s = 128 + kh; s < 136; s += 4){
      short8 bf[4];
      #pragma unroll
      for (int nt = 0; nt < 4; ++nt) bf[nt] = ldB(bpl + (s*4 + nt)*512);
      const int ub = (s - 128)*2 + (tg >> 1);
      #pragma unroll
      for (int mt = 0; mt < 2; ++mt){
        const float* rb = rbase[mt];
        float xu[5];
        #pragma unroll
        for (int i = 0; i < 5; ++i) xu[i] = rb[160 + ub*5 + i];
        float xv[40];
        #pragma unroll
        for (int q = 0; q < 10; ++q){
          const float4 v = *reinterpret_cast<const float4*>(rb + 160 + (tg&1)*40 + q*4);
          xv[q*4+0] = v.x; xv[q*4+1] = v.y; xv[q*4+2] = v.z; xv[q*4+3] = v.w;
        }
        float sv[8];
        #pragma unroll
        for (int t = 0; t < 8; ++t){
          float a = 0.f;
          #pragma unroll
          for (int i = 0; i < 5; ++i) a = fmaf(xu[i], xv[t*5+i], a);
          sv[t] = a;
        }
        const short8 af = mkfrag(sv);
        #pragma unroll
        for (int nt = 0; nt < 4; ++nt) acc[mt][nt] = MFMA(af, bf[nt], acc[mt][nt]);
      }
    }
    // --- 4-way K reduction + store ---
    __syncthreads();
    float* red = lx;
    if (kh != 0){
      #pragma unroll
      for (int mt = 0; mt < 2; ++mt)
        #pragma unroll
        for (int nt = 0; nt < 4; ++nt)
          #pragma unroll
          for (int r = 0; r < 4; ++r)
            red[mh*6144 + ((kh-1)*8 + mt*4 + nt)*256 + (tg*4 + r)*16 + col] = acc[mt][nt][r];
    }
    __syncthreads();
    if (kh == 0){
      #pragma unroll
      for (int mt = 0; mt < 2; ++mt)
        #pragma unroll
        for (int r = 0; r < 4; ++r){
          const int b = b0 + mh*32 + mt*16 + tg*4 + r;
          if (b < 20000){
            #pragma unroll
            for (int nt = 0; nt < 4; ++nt){
              float v = acc[mt][nt][r];
              #pragma unroll
              for (int w2 = 1; w2 < 4; ++w2)
                v += red[mh*6144 + ((w2-1)*8 + mt*4 + nt)*256 + (tg*4 + r)*16 + col];
              out[(size_t)b*240 + nt*16 + col] = v;
            }
          }
        }
    }

  } else if (g == 1){
    // ===== GEMM 1: out[:,64:160] (w*3+k), K=2560, 4-way M (mq) x 2-way K =====
    const unsigned short* bpl = wt + WT1_OFF + fo;
    const int mq = wv >> 1;
    const int kh = wv & 1;
    const float* rb = &lx[(mq*16 + col)*XS];

    float4v acc[3][2];
    #pragma unroll
    for (int k3 = 0; k3 < 3; ++k3)
      #pragma unroll
      for (int nt = 0; nt < 2; ++nt) acc[k3][nt] = z4;

    float w8[8];
    {
      const float4 v0 = *reinterpret_cast<const float4*>(rb + kh*32 + tg*8);
      const float4 v1 = *reinterpret_cast<const float4*>(rb + kh*32 + tg*8 + 4);
      w8[0]=v0.x; w8[1]=v0.y; w8[2]=v0.z; w8[3]=v0.w;
      w8[4]=v1.x; w8[5]=v1.y; w8[6]=v1.z; w8[7]=v1.w;
    }
    float x1w[24];
    #pragma unroll
    for (int q = 0; q < 6; ++q){
      const float4 v = *reinterpret_cast<const float4*>(rb + 64 + tg*24 + q*4);
      x1w[q*4+0] = v.x; x1w[q*4+1] = v.y; x1w[q*4+2] = v.z; x1w[q*4+3] = v.w;
    }

    // --- (0,1,1)+(1,0,1) folded: s in [0,64), K=A1*64+A0 ---
    for (int s = kh; s < 64; s += 2){
      const short8 bf0 = ldB(bpl + (s*2    )*512);
      const short8 bf1 = ldB(bpl + (s*2 + 1)*512);
      const int m = s >> 1;
      const float c0 = rb[64+m*3], c1 = rb[64+m*3+1], c2 = rb[64+m*3+2];
      float sv0[8], sv1[8], sv2[8];
      #pragma unroll
      for (int t = 0; t < 8; ++t){
        const float xw = w8[t];
        sv0[t] = xw*c0; sv1[t] = xw*c1; sv2[t] = xw*c2;
      }
      const short8 a0 = mkfrag(sv0), a1 = mkfrag(sv1), a2 = mkfrag(sv2);
      acc[0][0] = MFMA(a0, bf0, acc[0][0]);
      acc[0][1] = MFMA(a0, bf1, acc[0][1]);
      acc[1][0] = MFMA(a1, bf0, acc[1][0]);
      acc[1][1] = MFMA(a1, bf1, acc[1][1]);
      acc[2][0] = MFMA(a2, bf0, acc[2][0]);
      acc[2][1] = MFMA(a2, bf1, acc[2][1]);
    }
    // --- (1,2,1)+(2,1,1) folded: s in [64,80), K=v2*32+u1, precontracted ---
    for (int s = 64 + kh; s < 80; s += 2){
      const short8 bf0 = ldB(bpl + (s*2    )*512);
      const short8 bf1 = ldB(bpl + (s*2 + 1)*512);
      const int v2 = s - 64;
      float xq[5];
      #pragma unroll
      for (int j = 0; j < 5; ++j) xq[j] = rb[160 + v2*5 + j];
      // t3[kk][i] = sum_j C121[i][j][kk] * xq[j]
      float t3[3][3];
      #pragma unroll
      for (int kk = 0; kk < 3; ++kk)
        #pragma unroll
        for (int i = 0; i < 3; ++i){
          float a = 0.f;
          #pragma unroll
          for (int j = 0; j < 5; ++j){
            const double cd = T121.v[i][j][kk];
            if (NZ(cd)) a = fmaf((float)cd, xq[j], a);
          }
          t3[kk][i] = a;
        }
      float sv0[8], sv1[8], sv2[8];
      #pragma unroll
      for (int t = 0; t < 8; ++t){
        const float a0_ = x1w[t*3], a1_ = x1w[t*3+1], a2_ = x1w[t*3+2];
        sv0[t] = fmaf(a0_, t3[0][0], fmaf(a1_, t3[0][1], a2_*t3[0][2]));
        sv1[t] = fmaf(a0_, t3[1][0], fmaf(a1_, t3[1][1], a2_*t3[1][2]));
        sv2[t] = fmaf(a0_, t3[2][0], fmaf(a1_, t3[2][1], a2_*t3[2][2]));
      }
      const short8 a0 = mkfrag(sv0), a1 = mkfrag(sv1), a2 = mkfrag(sv2);
      acc[0][0] = MFMA(a0, bf0, acc[0][0]);
      acc[0][1] = MFMA(a0, bf1, acc[0][1]);
      acc[1][0] = MFMA(a1, bf0, acc[1][0]);
      acc[1][1] = MFMA(a1, bf1, acc[1][1]);
      acc[2][0] = MFMA(a2, bf0, acc[2][0]);
      acc[2][1] = MFMA(a2, bf1, acc[2][1]);
    }
    // --- 2-way K reduction + store (3 consecutive floats per (b,w)) ---
    __syncthreads();
    float* red = lx;
    if (kh == 1){
      #pragma unroll
      for (int k3 = 0; k3 < 3; ++k3)
        #pragma unroll
        for (int nt = 0; nt < 2; ++nt)
          #pragma unroll
          for (int r = 0; r < 4; ++r)
            red[mq*1536 + (k3*2 + nt)*256 + (tg*4 + r)*16 + col] = acc[k3][nt][r];
    }
    __syncthreads();
    if (kh == 0){
      #pragma unroll
      for (int r = 0; r < 4; ++r){
        const int b = b0 + mq*16 + tg*4 + r;
        if (b < 20000){
          #pragma unroll
          for (int nt = 0; nt < 2; ++nt){
            const int w2 = nt*16 + col;
            float* o = out + (size_t)b*240 + 64 + 3*w2;
            #pragma unroll
            for (int k3 = 0; k3 < 3; ++k3)
              o[k3] = acc[k3][nt][r]
                    + red[mq*1536 + (k3*2 + nt)*256 + (tg*4 + r)*16 + col];
          }
        }
      }
    }

  } else {
    // ===== GEMM 2: out[:,160:240] (w*5+k), K=2304, 4-way M (mq) x 2-way K =====
    const unsigned short* bpl = wt + WT2_OFF + fo;
    const int mq = wv >> 1;
    const int kh = wv & 1;
    const float* rb = &lx[(mq*16 + col)*XS];

    float4v acc[5] = { z4, z4, z4, z4, z4 };

    float w8[8];
    {
      const float4 v0 = *reinterpret_cast<const float4*>(rb + kh*32 + tg*8);
      const float4 v1 = *reinterpret_cast<const float4*>(rb + kh*32 + tg*8 + 4);
      w8[0]=v0.x; w8[1]=v0.y; w8[2]=v0.z; w8[3]=v0.w;
      w8[4]=v1.x; w8[5]=v1.y; w8[6]=v1.z; w8[7]=v1.w;
    }
    float x1w[24];
    #pragma unroll
    for (int q = 0; q < 6; ++q){
      const float4 v = *reinterpret_cast<const float4*>(rb + 64 + tg*24 + q*4);
      x1w[q*4+0] = v.x; x1w[q*4+1] = v.y; x1w[q*4+2] = v.z; x1w[q*4+3] = v.w;
    }

    // --- (0,2,2)+(2,0,2) folded: s in [0,32), K=v2*64+u0 ---
    for (int s = kh; s < 32; s += 2){
      const short8 bf = ldB(bpl + s*512);
      const int v2 = s >> 1;
      float xq[5];
      #pragma unroll
      for (int j = 0; j < 5; ++j) xq[j] = rb[160 + v2*5 + j];
      float sv[5][8];
      #pragma unroll
      for (int t = 0; t < 8; ++t){
        const float xw = w8[t];
        #pragma unroll
        for (int k5 = 0; k5 < 5; ++k5) sv[k5][t] = xw * xq[k5];
      }
      #pragma unroll
      for (int k5 = 0; k5 < 5; ++k5) acc[k5] = MFMA(mkfrag(sv[k5]), bf, acc[k5]);
    }
    // --- (1,1,2): s in [32,64), K=u*32+v, precontracted ---
    for (int s = 32 + kh; s < 64; s += 2){
      const short8 bf = ldB(bpl + s*512);
      const int u = s - 32;
      float xu[3];
      #pragma unroll
      for (int i = 0; i < 3; ++i) xu[i] = rb[64 + u*3 + i];
      // t5[kk][j] = sum_i C112[i][j][kk] * xu[i]
      float t5[5][3];
      #pragma unroll
      for (int kk = 0; kk < 5; ++kk)
        #pragma unroll
        for (int j = 0; j < 3; ++j){
          float a = 0.f;
          #pragma unroll
          for (int i = 0; i < 3; ++i){
            const double cd = T112.v[i][j][kk];
            if (NZ(cd)) a = fmaf((float)cd, xu[i], a);
          }
          t5[kk][j] = a;
        }
      float sv[5][8];
      #pragma unroll
      for (int t = 0; t < 8; ++t){
        const float b0_ = x1w[t*3], b1_ = x1w[t*3+1], b2_ = x1w[t*3+2];
        #pragma unroll
        for (int kk = 0; kk < 5; ++kk)
          sv[kk][t] = fmaf(b0_, t5[kk][0], fmaf(b1_, t5[kk][1], b2_*t5[kk][2]));
      }
      #pragma unroll
      for (int k5 = 0; k5 < 5; ++k5) acc[k5] = MFMA(mkfrag(sv[k5]), bf, acc[k5]);
    }
    // --- (2,2,2): s in [64,72), K=u*16+v, precontracted per-lane ---
    float x2w[40];
    #pragma unroll
    for (int q = 0; q < 10; ++q){
      const float4 v = *reinterpret_cast<const float4*>(rb + 160 + (tg&1)*40 + q*4);
      x2w[q*4+0] = v.x; x2w[q*4+1] = v.y; x2w[q*4+2] = v.z; x2w[q*4+3] = v.w;
    }
    for (int s = 64 + kh; s < 72; s += 2){
      const short8 bf = ldB(bpl + s*512);
      const int ub = (s - 64)*2 + (tg >> 1);
      float xu[5];
      #pragma unroll
      for (int i = 0; i < 5; ++i) xu[i] = rb[160 + ub*5 + i];
      // t5[kk][j] = sum_i C222[i][j][kk] * xu[i]
      float t5[5][5];
      #pragma unroll
      for (int kk = 0; kk < 5; ++kk)
        #pragma unroll
        for (int j = 0; j < 5; ++j){
          float a = 0.f;
          #pragma unroll
          for (int i = 0; i < 5; ++i){
            const double cd = T222.v[i][j][kk];
            if (NZ(cd)) a = fmaf((float)cd, xu[i], a);
          }
          t5[kk][j] = a;
        }
      float sv[5][8];
      #pragma unroll
      for (int t = 0; t < 8; ++t){
        #pragma unroll
        for (int kk = 0; kk < 5; ++kk){
          float a = 0.f;
          #pragma unroll
          for (int j = 0; j < 5; ++j) a = fmaf(x2w[t*5+j], t5[kk][j], a);
          sv[kk][t] = a;
        }
      }
      #pragma unroll
      for (int k5 = 0; k5 < 5; ++k5) acc[k5] = MFMA(mkfrag(sv[k5]), bf, acc[k5]);
    }
    // --- 2-way K reduction + store (5 consecutive floats per (b,w)) ---
    __syncthreads();
    float* red = lx;
    if (kh == 1){
      #pragma unroll
      for (int k5 = 0; k5 < 5; ++k5)
        #pragma unroll
        for (int r = 0; r < 4; ++r)
          red[mq*1280 + k5*256 + (tg*4 + r)*16 + col] = acc[k5][r];
    }
    __syncthreads();
    if (kh == 0){
      #pragma unroll
      for (int r = 0; r < 4; ++r){
        const int b = b0 + mq*16 + tg*4 + r;
        if (b < 20000){
          float* o = out + (size_t)b*240 + 160 + 5*col;
          #pragma unroll
          for (int k5 = 0; k5 < 5; ++k5)
            o[k5] = acc[k5][r] + red[mq*1280 + k5*256 + (tg*4 + r)*16 + col];
        }
      }
    }
  }
}

// ---------------------------------------------------------------------------
extern "C" void kernel_launch(void* const* d_in, const int* in_sizes, int n_in,
                              void* d_out, int out_size, void* d_ws, size_t ws_size,
                              hipStream_t stream){
  (void)in_sizes; (void)n_in; (void)out_size; (void)ws_size;
  const float* x = (const float*)d_in[0];
  const float* w[11];
  for (int i = 0; i < 11; ++i) w[i] = (const float*)d_in[1 + i];
  unsigned short* wt = (unsigned short*)d_ws;
  float* out = (float*)d_out;

  dim3 gp(136, 3);
  tsq_prep<<<gp, 256, 0, stream>>>(w[0], w[1], w[2], w[3], w[4], w[5],
                                   w[6], w[7], w[8], w[9], w[10], wt);
  dim3 gm(3, 313);
  tsq_main<<<gm, 512, 0, stream>>>(x, wt, out);
}